// Round 8
// baseline (241.484 us; speedup 1.0000x reference)
//
#include <hip/hip_runtime.h>
#include <hip/hip_bf16.h>

#define DIM_K 4096
#define DIM_N 4096
#define M_TOK 8192

typedef __attribute__((ext_vector_type(8))) short bf16x8;
typedef __attribute__((ext_vector_type(4))) float f32x4;

typedef const __attribute__((address_space(1))) unsigned int gu32;
typedef __attribute__((address_space(3))) unsigned int lu32;

__device__ __forceinline__ unsigned short f2bf(float f) {
  unsigned int u = __float_as_uint(f);
  u += 0x7FFFu + ((u >> 16) & 1u);   // round-to-nearest-even
  return (unsigned short)(u >> 16);
}

__device__ __forceinline__ void gload_lds16(const void* g, void* l) {
  __builtin_amdgcn_global_load_lds((gu32*)g, (lu32*)l, 16, 0, 0);
}

// ---------------- pre-pass 1: x fp32 [M][K] -> bf16 [M][K] ----------------
__global__ void cvt_x_kernel(const float* __restrict__ x,
                             unsigned short* __restrict__ xb, int n4) {
  int idx = blockIdx.x * blockDim.x + threadIdx.x;
  int stride = gridDim.x * blockDim.x;
  for (int i = idx; i < n4; i += stride) {
    float4 v = reinterpret_cast<const float4*>(x)[i];
    ushort4 o;
    o.x = f2bf(v.x); o.y = f2bf(v.y); o.z = f2bf(v.z); o.w = f2bf(v.w);
    reinterpret_cast<ushort4*>(xb)[i] = o;
  }
}

// ---------- pre-pass 2: W fp32 [K][N] -> Wt bf16 [N][K] (transpose) --------
__global__ void cvt_wt_kernel(const float* __restrict__ W,
                              unsigned short* __restrict__ Wt) {
  __shared__ unsigned short tile[32][33];
  const int k0 = blockIdx.x * 32;
  const int n0 = blockIdx.y * 32;
  const int kendn = (n0 < 1024) ? 1024 : (n0 < 2048 ? 2048 : 4096);
  if (k0 >= kendn) return;
  const int tx = threadIdx.x;  // 0..31
  const int ty = threadIdx.y;  // 0..7
#pragma unroll
  for (int j = 0; j < 4; ++j) {
    int k = k0 + ty + 8 * j;
    tile[ty + 8 * j][tx] = f2bf(W[(size_t)k * DIM_N + n0 + tx]);
  }
  __syncthreads();
#pragma unroll
  for (int j = 0; j < 4; ++j) {
    int n = n0 + ty + 8 * j;
    Wt[(size_t)n * DIM_K + k0 + tx] = tile[tx][ty + 8 * j];
  }
}

// ---------------------------------------------------------------------------
// 256x256 GEMM, bf16 16x16x32, 8 single-barrier windows per 2 K-tiles,
// 1-phase read skew. Window p = { RD(p+1); STG; MFMA(p) [operands read in
// window p-1]; [vmcnt(6) @ph3/ph7]; lgkmcnt(0); s_barrier }.
//
// Cross-wave RAW (reads of staged data): read happens only AFTER a barrier
// preceded (in every wave) by a vmcnt covering that staging:
//   vmcnt(6)@ph3 allows {ph2(2),ph3(4)} outstanding => prev-ph6/7/8 stages
//     (ALL of buf1's tile `to`) complete => ph4/ph5/ph6 reads of buf1 safe.
//   vmcnt(6)@ph7 allows {ph6(2),ph7(4)} outstanding => ph2/ph3/ph4 stages
//     (ALL of buf0's tile t2) complete => ph8/next-ph1/next-ph2 reads safe.
// Cross-wave WAR (STG overwriting read regions): trailing lgkmcnt(0) in
// EVERY window drains each wave's reads before it passes the barrier =>
// a STG in any later window is safe. Stage slots vs last readers:
//   ph2 B-h0(t2->buf0)  [buf0-B readers: b0@prev-ph8, b1@ph1]
//   ph3 B-h1+A-h0(t2->buf0) [buf0-A readers: a0@prev-ph8, a1@ph2]
//   ph4 A-h1(t2->buf0)
//   ph6 B-h0(t3->buf1)  [buf1-B readers: b0@ph4, b1@ph5]
//   ph7 B-h1+A-h1(t3->buf1) [buf1-A readers: a0@ph4, a1@ph6]
//   ph8 A-h0(t3->buf1)
// Staging lead: 3 windows (~900 cyc) >= HBM latency.
// ---------------------------------------------------------------------------
__global__ __launch_bounds__(512, 2) void gemm_kernel(
    const unsigned short* __restrict__ A,   // [M][K] bf16
    const unsigned short* __restrict__ Bt,  // [N][K] bf16
    float* __restrict__ C) {
  __shared__ unsigned short lds[65536];  // 128 KB

  const int tid = threadIdx.x;
  const int lane = tid & 63;
  const int w = tid >> 6;   // 0..7
  const int wr = w >> 2;    // 0..1 : M half (128 rows)
  const int wc = w & 3;     // 0..3 : N quarter (64 cols)

  const int bid = blockIdx.x;
  const int bx = bid & 31;
  const int by = 15 - (bid >> 5);    // heavy (kend=4096) first
  const int m0 = bx * 256;
  const int n0 = by * 256;
  const int kend = (n0 < 1024) ? 1024 : (n0 < 2048 ? 2048 : 4096);
  const int nk64 = kend >> 6;        // 16 / 32 / 64
  const int nIter = nk64 >> 1;

  const unsigned short* Ab = A + (size_t)m0 * DIM_K;
  const unsigned short* Bb = Bt + (size_t)n0 * DIM_K;

  // staging: lane -> row (h*128 + w*16 + l*8 + lane/8), src k-chunk inverse-swz
  const int rloc = lane >> 3;
  const int kterm = ((lane & 7) ^ rloc) << 3;
  size_t srcs[2][2];
#pragma unroll
  for (int h = 0; h < 2; ++h)
#pragma unroll
    for (int l = 0; l < 2; ++l)
      srcs[h][l] = (size_t)(h * 128 + w * 16 + l * 8 + rloc) * DIM_K + kterm;

  // fragment geometry (16x16x32: row/col = lane&15, k = (lane>>4)*8+j)
  const int l15 = lane & 15;
  const int kb = (lane >> 4) << 3;
  const int swz = (l15 & 7) << 3;
  const int arow = wr * 128 + l15;
  const int brow = wc * 64 + l15;

#define SB() __builtin_amdgcn_sched_barrier(0)
#define BAR() __builtin_amdgcn_s_barrier()
#define LGKM0() asm volatile("s_waitcnt lgkmcnt(0)" ::: "memory")
#define VM6LGKM0() asm volatile("s_waitcnt vmcnt(6) lgkmcnt(0)" ::: "memory")

#define AFR(buf, mi, ks) (*(const bf16x8*)&lds[(buf)*32768 + \
    (arow + (mi)*16)*64 + ((((ks)<<5) + kb) ^ swz)])
#define BFR(buf, ni, ks) (*(const bf16x8*)&lds[(buf)*32768 + 16384 + \
    (brow + (ni)*16)*64 + ((((ks)<<5) + kb) ^ swz)])

#define STG(Base, op, h, kt, buf)                                            \
  do {                                                                       \
    gload_lds16(Base + srcs[h][0] + ((size_t)(kt) << 6),                     \
                &lds[(buf)*32768 + (op)*16384 + (h)*8192 + (w*2)*512]);      \
    gload_lds16(Base + srcs[h][1] + ((size_t)(kt) << 6),                     \
                &lds[(buf)*32768 + (op)*16384 + (h)*8192 + (w*2+1)*512]);    \
  } while (0)

#define RDA0B0(buf)                                                          \
  { _Pragma("unroll") for (int m2 = 0; m2 < 4; ++m2)                         \
    _Pragma("unroll") for (int ks = 0; ks < 2; ++ks) a0[m2*2+ks] = AFR(buf, m2, ks); \
    _Pragma("unroll") for (int n2 = 0; n2 < 2; ++n2)                         \
    _Pragma("unroll") for (int ks = 0; ks < 2; ++ks) b0[n2*2+ks] = BFR(buf, n2, ks); }
#define RDA1(buf)                                                            \
  { _Pragma("unroll") for (int m2 = 0; m2 < 4; ++m2)                         \
    _Pragma("unroll") for (int ks = 0; ks < 2; ++ks) a1[m2*2+ks] = AFR(buf, 4+m2, ks); }
#define RDB1(buf)                                                            \
  { _Pragma("unroll") for (int n2 = 0; n2 < 2; ++n2)                         \
    _Pragma("unroll") for (int ks = 0; ks < 2; ++ks) b1[n2*2+ks] = BFR(buf, 2+n2, ks); }

#define MFQ(mh, nh, AR, BR)                                                  \
  do {                                                                       \
    __builtin_amdgcn_s_setprio(1);                                           \
    _Pragma("unroll") for (int m2 = 0; m2 < 4; ++m2)                         \
      _Pragma("unroll") for (int n2 = 0; n2 < 2; ++n2)                       \
        _Pragma("unroll") for (int ks = 0; ks < 2; ++ks)                     \
          acc[(mh)*4+m2][(nh)*2+n2] = __builtin_amdgcn_mfma_f32_16x16x32_bf16( \
              AR[m2*2+ks], BR[n2*2+ks], acc[(mh)*4+m2][(nh)*2+n2], 0, 0, 0); \
    __builtin_amdgcn_s_setprio(0);                                           \
  } while (0)

  f32x4 acc[8][4];
#pragma unroll
  for (int i = 0; i < 8; ++i)
#pragma unroll
    for (int j = 0; j < 4; ++j) acc[i][j] = (f32x4){0.f, 0.f, 0.f, 0.f};

  bf16x8 a0[8], a1[8], b0[4], b1[4];

  // --- prologue: tile0 -> buf0 (8 loads), tile1 -> buf1 (8 loads)
  STG(Ab, 0, 0, 0, 0); STG(Ab, 0, 1, 0, 0);
  STG(Bb, 1, 0, 0, 0); STG(Bb, 1, 1, 0, 0);
  STG(Ab, 0, 0, 1, 1); STG(Ab, 0, 1, 1, 1);
  STG(Bb, 1, 0, 1, 1); STG(Bb, 1, 1, 1, 1);
  asm volatile("s_waitcnt vmcnt(8)" ::: "memory");  // tile0 resident
  BAR(); SB();
  RDA0B0(0);                                        // tile0 a0,b0 (for ph1)
  SB();

  for (int it = 0; it < nIter; ++it) {
    int t2 = 2 * it + 2; if (t2 > nk64 - 1) t2 = nk64 - 1;
    int t3 = 2 * it + 3; if (t3 > nk64 - 1) t3 = nk64 - 1;

    // ph1: RD b1(buf0) ; MFMA Q00(a0,b0)
    RDB1(0); SB();
    MFQ(0, 0, a0, b0); SB();
    LGKM0(); SB(); BAR(); SB();
    // ph2: RD a1(buf0) ; STG B-h0(t2->buf0) ; MFMA Q01(a0,b1)
    RDA1(0); SB();
    STG(Bb, 1, 0, t2, 0); SB();
    MFQ(0, 1, a0, b1); SB();
    LGKM0(); SB(); BAR(); SB();
    // ph3: STG B-h1+A-h0(t2->buf0) ; MFMA Q10(a1,b0) ; vmcnt(6)
    STG(Bb, 1, 1, t2, 0); STG(Ab, 0, 0, t2, 0); SB();
    MFQ(1, 0, a1, b0); SB();
    VM6LGKM0(); SB(); BAR(); SB();
    // ph4: RD a0,b0(buf1) ; STG A-h1(t2->buf0) ; MFMA Q11(a1,b1)
    RDA0B0(1); SB();
    STG(Ab, 0, 1, t2, 0); SB();
    MFQ(1, 1, a1, b1); SB();
    LGKM0(); SB(); BAR(); SB();

    // ph5: RD b1(buf1) ; MFMA Q00(a0,b0)
    RDB1(1); SB();
    MFQ(0, 0, a0, b0); SB();
    LGKM0(); SB(); BAR(); SB();
    // ph6: RD a1(buf1) ; STG B-h0(t3->buf1) ; MFMA Q01(a0,b1)
    RDA1(1); SB();
    STG(Bb, 1, 0, t3, 1); SB();
    MFQ(0, 1, a0, b1); SB();
    LGKM0(); SB(); BAR(); SB();
    // ph7: STG B-h1+A-h1(t3->buf1) ; MFMA Q10(a1,b0) ; vmcnt(6)
    STG(Bb, 1, 1, t3, 1); STG(Ab, 0, 1, t3, 1); SB();
    MFQ(1, 0, a1, b0); SB();
    VM6LGKM0(); SB(); BAR(); SB();
    // ph8: RD a0,b0(buf0, t2) ; STG A-h0(t3->buf1) ; MFMA Q11(a1,b1)
    RDA0B0(0); SB();
    STG(Ab, 0, 0, t3, 1); SB();
    MFQ(1, 1, a1, b1); SB();
    LGKM0(); SB(); BAR(); SB();
  }
  asm volatile("s_waitcnt vmcnt(0)" ::: "memory");  // drain tail stages

  // --- epilogue: C/D layout col=lane&15, row=(lane>>4)*4+reg
  const int crow0 = m0 + wr * 128 + (lane >> 4) * 4;
  const int ccol0 = n0 + wc * 64 + l15;
#pragma unroll
  for (int mi = 0; mi < 8; ++mi)
#pragma unroll
    for (int ni = 0; ni < 4; ++ni) {
      float* Cp = C + (size_t)(crow0 + mi * 16) * DIM_N + ccol0 + ni * 16;
#pragma unroll
      for (int r2 = 0; r2 < 4; ++r2) Cp[(size_t)r2 * DIM_N] = acc[mi][ni][r2];
    }
#undef AFR
#undef BFR
#undef STG
#undef RDA0B0
#undef RDA1
#undef RDB1
#undef MFQ
#undef SB
#undef BAR
#undef LGKM0
#undef VM6LGKM0
}

extern "C" void kernel_launch(void* const* d_in, const int* in_sizes, int n_in,
                              void* d_out, int out_size, void* d_ws,
                              size_t ws_size, hipStream_t stream) {
  const float* x = (const float*)d_in[0];
  const float* W = (const float*)d_in[1];
  float* out = (float*)d_out;

  unsigned short* xb = (unsigned short*)d_ws;                  // 64 MB
  unsigned short* wt = xb + (size_t)M_TOK * DIM_K;             // 32 MB

  cvt_x_kernel<<<2048, 256, 0, stream>>>(x, xb, M_TOK * DIM_K / 4);
  cvt_wt_kernel<<<dim3(DIM_K / 32, DIM_N / 32), dim3(32, 8), 0, stream>>>(W, wt);
  gemm_kernel<<<512, 512, 0, stream>>>(xb, wt, out);
}